// Round 7
// baseline (18830.348 us; speedup 1.0000x reference)
//
#include <hip/hip_runtime.h>
#include <math.h>

#define T_STEPS 4096
#define HID     2048
#define MOD     256
#define INSZ    1024
#define REST    1792              // HID - MOD
#define NFAST   8                 // fast blocks (module-0 engine)
#define NWIDEB  32                // wide blocks, 8 waves each -> 256 wide waves

typedef unsigned long long u64;

// ---------------------------------------------------------------------------
// Agent-scope (device-coherent) helpers + packet utils
// ---------------------------------------------------------------------------
static __device__ __forceinline__ u64 agent_load_u64(const u64* p) {
    return __hip_atomic_load((u64*)p, __ATOMIC_RELAXED, __HIP_MEMORY_SCOPE_AGENT);
}
static __device__ __forceinline__ void agent_store_u64(u64* p, u64 v) {
    __hip_atomic_store(p, v, __ATOMIC_RELAXED, __HIP_MEMORY_SCOPE_AGENT);
}
static __device__ __forceinline__ u64 mkpkt(int t, float v) {
    return ((u64)(unsigned)t << 32) | (u64)__float_as_uint(v);
}
static __device__ __forceinline__ unsigned ptag(u64 v) { return (unsigned)(v >> 32); }
static __device__ __forceinline__ float    pval(u64 v) { return __uint_as_float((unsigned)v); }
static __device__ __forceinline__ int nact(int t) {
    int a = __builtin_ctz(t) + 1; return a > 8 ? 8 : a;
}
static __device__ __forceinline__ float tanh_fast(float x) {
    x = fminf(fmaxf(x, -15.f), 15.f);     // avoid inf/inf
    float e = __expf(2.f * x);
    return (e - 1.f) / (e + 1.f);
}

// ---------------------------------------------------------------------------
// Kernel 1: U = x @ W_ih^T + (b_ih + b_hh), written into out[t, i].
// 128x128 tile, BK=8, 256 threads, 8x8 per thread, fp32.
// ---------------------------------------------------------------------------
#define BM 128
#define BN 128
#define BK 8

__global__ __launch_bounds__(256) void gemm_u(
    const float* __restrict__ x, const float* __restrict__ Wih,
    const float* __restrict__ bih, const float* __restrict__ bhh,
    float* __restrict__ out)
{
    __shared__ float As[BK][BM];
    __shared__ float Bs[BK][BN];

    const int tid = threadIdx.x;
    const int t0 = blockIdx.y * BM;
    const int i0 = blockIdx.x * BN;
    const int tx = tid & 15;
    const int ty = tid >> 4;
    const int arow = tid >> 1;
    const int acol = (tid & 1) * 4;

    float acc[8][8];
#pragma unroll
    for (int a = 0; a < 8; ++a)
#pragma unroll
        for (int b = 0; b < 8; ++b) acc[a][b] = 0.0f;

    for (int k0 = 0; k0 < INSZ; k0 += BK) {
        float4 av = *(const float4*)(x   + (size_t)(t0 + arow) * INSZ + k0 + acol);
        float4 bv = *(const float4*)(Wih + (size_t)(i0 + arow) * INSZ + k0 + acol);
        __syncthreads();
        As[acol + 0][arow] = av.x; As[acol + 1][arow] = av.y;
        As[acol + 2][arow] = av.z; As[acol + 3][arow] = av.w;
        Bs[acol + 0][arow] = bv.x; Bs[acol + 1][arow] = bv.y;
        Bs[acol + 2][arow] = bv.z; Bs[acol + 3][arow] = bv.w;
        __syncthreads();
#pragma unroll
        for (int kk = 0; kk < BK; ++kk) {
            float a[8], b[8];
            *(float4*)&a[0] = *(const float4*)&As[kk][ty * 8];
            *(float4*)&a[4] = *(const float4*)&As[kk][ty * 8 + 4];
            *(float4*)&b[0] = *(const float4*)&Bs[kk][tx * 8];
            *(float4*)&b[4] = *(const float4*)&Bs[kk][tx * 8 + 4];
#pragma unroll
            for (int ri = 0; ri < 8; ++ri)
#pragma unroll
                for (int ci = 0; ci < 8; ++ci)
                    acc[ri][ci] = fmaf(a[ri], b[ci], acc[ri][ci]);
        }
    }

    float bias[8];
#pragma unroll
    for (int ci = 0; ci < 8; ++ci) {
        int i = i0 + tx * 8 + ci;
        bias[ci] = bih[i] + bhh[i];
    }
#pragma unroll
    for (int ri = 0; ri < 8; ++ri) {
        int t = t0 + ty * 8 + ri;
#pragma unroll
        for (int ci = 0; ci < 8; ++ci) {
            int i = i0 + tx * 8 + ci;
            out[(size_t)t * HID + i] = acc[ri][ci] + bias[ci];
        }
    }
}

// ---------------------------------------------------------------------------
// Kernel 2: split persistent recurrence.
//   comm layout (u64): h0comm[2][256] at 0, restcomm[2][1792] at +512.
//   restcomm parity = (producing even step >> 1) & 1.
// Fast blocks (0..7): 512 thr; thread tau: row r=32f+(tau>>4), lam=tau&15,
//   W[r][lam+16k] k<128 in VGPRs. Running dot D_r updated by deltas of the
//   changed prefix (module-0 deltas every step, rest deltas at odd t).
// Wide blocks (8..39): 8 waves each, wave w owns rest rows {256m+w}; runs at
//   even t only, exactly the round-5 register-h structure.
// Parity-reuse safety: every published packet's VALUE data-depends on the
// consumed inputs, so observing tag T from a producer certifies all its
// earlier consumes completed (per-location coherence gives monotone reads).
// ---------------------------------------------------------------------------
__global__ __launch_bounds__(512) void cwrnn_rec(
    float* __restrict__ out, const float* __restrict__ Whh,
    u64* __restrict__ comm)
{
    u64* h0c = comm;            // [2][256]
    u64* rc  = comm + 512;      // [2][1792]

    __shared__ float dlt[HID];  // used by fast blocks only

    if (blockIdx.x < NFAST) {
        // ================= FAST: module-0 engine =================
        const int tau = threadIdx.x;             // 0..511
        const int r   = (blockIdx.x << 5) + (tau >> 4);   // owned row
        const int lam = tau & 15;

        float wreg[128];
        {
            const float* wr = Whh + (size_t)r * HID + lam;
#pragma unroll
            for (int k = 0; k < 128; ++k) wreg[k] = wr[16 * k];
        }
        float D = 0.f;
        float old0 = 0.f;                         // h0 col = tau (tau<256)
        float oldr0 = 0.f, oldr1 = 0.f, oldr2 = 0.f, oldr3 = 0.f; // rest cols

        for (int t = 1; t <= T_STEPS; ++t) {
            float Upf = out[(size_t)(t - 1) * HID + r];   // U, GEMM output

            if (t > 1) {
                const int Ap = nact(t - 1);               // changed modules
                const unsigned need = (unsigned)(t - 1);

                if (tau < 256) {                          // module-0 deltas
                    const u64* p = h0c + (size_t)((t - 1) & 1) * MOD + tau;
                    u64 v = agent_load_u64(p);
                    int bail = 1 << 27;
                    while (ptag(v) < need && --bail) v = agent_load_u64(p);
                    float nv = pval(v);
                    dlt[tau] = nv - old0; old0 = nv;
                }
                if ((t & 1) && Ap >= 2 && tau < 64 * (Ap - 1)) { // rest deltas
                    const u64* p = rc + (size_t)(((t - 1) >> 1) & 1) * REST + 4 * tau;
                    u64 v0 = agent_load_u64(p + 0), v1 = agent_load_u64(p + 1);
                    u64 v2 = agent_load_u64(p + 2), v3 = agent_load_u64(p + 3);
                    int bail = 1 << 27;
                    while ((ptag(v0) < need || ptag(v1) < need ||
                            ptag(v2) < need || ptag(v3) < need) && --bail) {
                        v0 = agent_load_u64(p + 0); v1 = agent_load_u64(p + 1);
                        v2 = agent_load_u64(p + 2); v3 = agent_load_u64(p + 3);
                    }
                    const int c = 256 + 4 * tau;
                    float n0 = pval(v0), n1 = pval(v1), n2 = pval(v2), n3 = pval(v3);
                    dlt[c + 0] = n0 - oldr0; oldr0 = n0;
                    dlt[c + 1] = n1 - oldr1; oldr1 = n1;
                    dlt[c + 2] = n2 - oldr2; oldr2 = n2;
                    dlt[c + 3] = n3 - oldr3; oldr3 = n3;
                }
                __syncthreads();

                float acc = 0.f;
#pragma unroll
                for (int mm = 0; mm < 8; ++mm) {          // static wreg index
                    if (mm < Ap) {
#pragma unroll
                        for (int kk = 0; kk < 16; ++kk)
                            acc = fmaf(wreg[mm * 16 + kk],
                                       dlt[mm * MOD + lam + 16 * kk], acc);
                    }
                }
                acc += __shfl_xor(acc, 1, 64);
                acc += __shfl_xor(acc, 2, 64);
                acc += __shfl_xor(acc, 4, 64);
                acc += __shfl_xor(acc, 8, 64);            // sum over 16-group
                D += acc;
            }

            float hv = tanh_fast(Upf + D);
            if (lam == 0) {
                agent_store_u64(h0c + (size_t)(t & 1) * MOD + r, mkpkt(t, hv));
                out[(size_t)(t - 1) * HID + r] = hv;
            }
            __syncthreads();   // dlt stable before next step's writes
        }
    } else {
        // ================= WIDE: modules 1..7, even steps =================
        const int lane = threadIdx.x & 63;
        const int w    = (blockIdx.x - NFAST) * 8 + (threadIdx.x >> 6); // 0..255

        float4 hreg[8];
#pragma unroll
        for (int j = 0; j < 8; ++j) hreg[j] = make_float4(0.f, 0.f, 0.f, 0.f);

        for (int t = 2; t <= T_STEPS; t += 2) {
            const int A = nact(t);                 // >= 2
            float* orow = out + (size_t)(t - 1) * HID;
            float upf = (lane >= 1 && lane < A) ? orow[lane * MOD + w] : 0.f;

            // consume rest(t-2) (landed long ago; certify-verified spin)
            if (t >= 4) {
                const int Ar = nact(t - 2);
                const unsigned needr = (unsigned)(t - 2);
                const u64* rp = rc + (size_t)(((t - 2) >> 1) & 1) * REST + 4 * lane;
#pragma unroll
                for (int m = 1; m < 8; ++m) {
                    if (m < Ar) {
                        const u64* p = rp + (m - 1) * MOD;
                        u64 v0 = agent_load_u64(p + 0), v1 = agent_load_u64(p + 1);
                        u64 v2 = agent_load_u64(p + 2), v3 = agent_load_u64(p + 3);
                        int bail = 1 << 27;
                        while ((ptag(v0) < needr || ptag(v1) < needr ||
                                ptag(v2) < needr || ptag(v3) < needr) && --bail) {
                            v0 = agent_load_u64(p + 0); v1 = agent_load_u64(p + 1);
                            v2 = agent_load_u64(p + 2); v3 = agent_load_u64(p + 3);
                        }
                        hreg[m] = make_float4(pval(v0), pval(v1), pval(v2), pval(v3));
                    }
                }
            }
            // poll h0(t-1) (odd parity slots) — the real wait
            {
                const unsigned need = (unsigned)(t - 1);
                const u64* p = h0c + MOD + 4 * lane;     // parity 1
                u64 v0 = agent_load_u64(p + 0), v1 = agent_load_u64(p + 1);
                u64 v2 = agent_load_u64(p + 2), v3 = agent_load_u64(p + 3);
                int bail = 1 << 27;
                while ((ptag(v0) < need || ptag(v1) < need ||
                        ptag(v2) < need || ptag(v3) < need) && --bail) {
                    __builtin_amdgcn_s_sleep(1);
                    v0 = agent_load_u64(p + 0); v1 = agent_load_u64(p + 1);
                    v2 = agent_load_u64(p + 2); v3 = agent_load_u64(p + 3);
                }
                hreg[0] = make_float4(pval(v0), pval(v1), pval(v2), pval(v3));
            }

            // inactive modules: out[t-1] and out[t] (h(t+1)=h(t) on rest)
#pragma unroll
            for (int j = 1; j < 8; ++j) {
                if (j >= A && w == (j - A)) {
                    *(float4*)(orow + j * MOD + 4 * lane) = hreg[j];
                    if (t < T_STEPS)
                        *(float4*)(orow + HID + j * MOD + 4 * lane) = hreg[j];
                }
            }
            if (t == 2 && w < 7)   // out[0] rest rows = h(1) rest = 0
                *(float4*)(out + (size_t)(w + 1) * MOD + 4 * lane) =
                    make_float4(0.f, 0.f, 0.f, 0.f);

            // active rest rows: full dots, pairs
            u64* rdst = rc + (size_t)((t >> 1) & 1) * REST;
            int m = 1;
            for (; m + 1 < A; m += 2) {
                const int ra = m * MOD + w;
                const int rb2 = ra + MOD;
                const float4* wa = (const float4*)(Whh + (size_t)ra * HID);
                const float4* wb = (const float4*)(Whh + (size_t)rb2 * HID);
                float4 sa = make_float4(0.f, 0.f, 0.f, 0.f);
                float4 sb = make_float4(0.f, 0.f, 0.f, 0.f);
#pragma unroll
                for (int j = 0; j < 8; ++j) {
                    float4 a = wa[lane + 64 * j];
                    float4 b = wb[lane + 64 * j];
                    sa.x = fmaf(a.x, hreg[j].x, sa.x);
                    sa.y = fmaf(a.y, hreg[j].y, sa.y);
                    sa.z = fmaf(a.z, hreg[j].z, sa.z);
                    sa.w = fmaf(a.w, hreg[j].w, sa.w);
                    sb.x = fmaf(b.x, hreg[j].x, sb.x);
                    sb.y = fmaf(b.y, hreg[j].y, sb.y);
                    sb.z = fmaf(b.z, hreg[j].z, sb.z);
                    sb.w = fmaf(b.w, hreg[j].w, sb.w);
                }
                float acca = (sa.x + sa.y) + (sa.z + sa.w);
                float accb = (sb.x + sb.y) + (sb.z + sb.w);
#pragma unroll
                for (int off = 32; off; off >>= 1) {
                    acca += __shfl_xor(acca, off, 64);
                    accb += __shfl_xor(accb, off, 64);
                }
                float ua = __shfl(upf, m, 64);
                float ub = __shfl(upf, m + 1, 64);
                float hva = tanh_fast(ua + acca);
                float hvb = tanh_fast(ub + accb);
                if (lane == 0) {
                    agent_store_u64(rdst + (ra - MOD),  mkpkt(t, hva));
                    agent_store_u64(rdst + (rb2 - MOD), mkpkt(t, hvb));
                    orow[ra] = hva; orow[rb2] = hvb;
                    if (t < T_STEPS) { orow[HID + ra] = hva; orow[HID + rb2] = hvb; }
                }
            }
            if (m < A) {
                const int rr = m * MOD + w;
                const float4* wr = (const float4*)(Whh + (size_t)rr * HID);
                float4 s = make_float4(0.f, 0.f, 0.f, 0.f);
#pragma unroll
                for (int j = 0; j < 8; ++j) {
                    float4 a = wr[lane + 64 * j];
                    s.x = fmaf(a.x, hreg[j].x, s.x);
                    s.y = fmaf(a.y, hreg[j].y, s.y);
                    s.z = fmaf(a.z, hreg[j].z, s.z);
                    s.w = fmaf(a.w, hreg[j].w, s.w);
                }
                float acc = (s.x + s.y) + (s.z + s.w);
#pragma unroll
                for (int off = 32; off; off >>= 1) acc += __shfl_xor(acc, off, 64);
                float um = __shfl(upf, m, 64);
                float hv = tanh_fast(um + acc);
                if (lane == 0) {
                    agent_store_u64(rdst + (rr - MOD), mkpkt(t, hv));
                    orow[rr] = hv;
                    if (t < T_STEPS) orow[HID + rr] = hv;
                }
            }
        }
    }
}

// ---------------------------------------------------------------------------
extern "C" void kernel_launch(void* const* d_in, const int* in_sizes, int n_in,
                              void* d_out, int out_size, void* d_ws, size_t ws_size,
                              hipStream_t stream) {
    const float* x   = (const float*)d_in[0];
    const float* Wih = (const float*)d_in[1];
    const float* Whh = (const float*)d_in[2];
    const float* bih = (const float*)d_in[3];
    const float* bhh = (const float*)d_in[4];
    float* out = (float*)d_out;
    u64* comm = (u64*)d_ws;

    // tags must start at 0: (2*256 + 2*1792) u64 = 32 KB
    hipMemsetAsync(d_ws, 0, (size_t)(512 + 2 * REST) * sizeof(u64), stream);

    dim3 g1(HID / BN, T_STEPS / BM);        // (16, 32)
    gemm_u<<<g1, 256, 0, stream>>>(x, Wih, bih, bhh, out);
    cwrnn_rec<<<NFAST + NWIDEB, 512, 0, stream>>>(out, Whh, comm);
}